// Round 1
// baseline (1082.334 us; speedup 1.0000x reference)
//
#include <hip/hip_runtime.h>
#include <stdint.h>

#define ALPHA 0.2f
#define MOMENTUM 0.8f
#define C_TOK 65536
#define DIM 768
#define MSLOT 25
#define KP 832          // 768 (text) + 25 (S) + 39 pad
#define NB_SEG 256

typedef __attribute__((ext_vector_type(8))) short short8;
typedef __attribute__((ext_vector_type(4))) float f32x4;

// ---------- workspace layout (bytes) ----------
#define OFF_BT   0ull
#define OFF_CBF  1277952ull
#define OFF_CMAX 1327104ull
#define OFF_LACC 1327232ull
#define OFF_BIG  1327360ull
// big-region, image phase
#define BO_IBF   0ull
#define BO_RAWI  100663296ull
#define BO_PART  109051904ull
#define BO_IDX   128712704ull
#define BO_SCV   128974848ull
#define BO_RNI   129236992ull
#define BO_CNTP  129499136ull
#define BIG_SZ   129524736ull
// big-region, text phase (after image phase is done)
#define BO_A     0ull
#define BO_RAWT  109051904ull
#define BO_RNT   117440512ull
#define WS_NEED  (OFF_BIG + BIG_SZ)

__device__ __forceinline__ float bf2f(unsigned short u) {
  union { float f; unsigned int i; } v; v.i = ((unsigned int)u) << 16; return v.f;
}
__device__ __forceinline__ unsigned short f2bf(float f) {
  union { float f; unsigned int i; } v; v.f = f;
  unsigned int x = v.i;
  unsigned int r = x + 0x7fffu + ((x >> 16) & 1u);
  return (unsigned short)(r >> 16);
}
__device__ __forceinline__ unsigned int enc_f(float f) {
  union { float f; unsigned int u; } v; v.f = f;
  return (v.u & 0x80000000u) ? ~v.u : (v.u | 0x80000000u);
}
__device__ __forceinline__ float dec_f(unsigned int e) {
  union { float f; unsigned int u; } v;
  v.u = (e & 0x80000000u) ? (e & 0x7fffffffu) : ~e;
  return v.f;
}
__device__ __forceinline__ float wave_red_sum(float v) {
  #pragma unroll
  for (int m = 32; m >= 1; m >>= 1) v += __shfl_xor(v, m, 64);
  return v;
}
typedef const __attribute__((address_space(1))) void* gvp;
typedef __attribute__((address_space(3))) void* lvp;
__device__ __forceinline__ void gload_lds16(const void* g, void* l) {
  __builtin_amdgcn_global_load_lds((gvp)(uintptr_t)g, (lvp)(uint32_t)(uintptr_t)l, 16, 0, 0);
}

// ---------- K0: build Bt [768][832] = [W1^T ; P ; 0] and Cbf [32][768] ----------
__global__ __launch_bounds__(256) void k_build_b(const float* __restrict__ w,
                                                 const float* __restrict__ cache,
                                                 unsigned short* __restrict__ Bt,
                                                 unsigned short* __restrict__ Cbf) {
  int n = blockIdx.x;
  int t = threadIdx.x;
  const float* wrow = w + (size_t)n * 1536;
  unsigned short* brow = Bt + (size_t)n * KP;
  for (int k = t; k < DIM; k += 256) brow[k] = f2bf(wrow[k]);
  int wv = t >> 6, l = t & 63;
  for (int s = wv; s < MSLOT; s += 4) {
    float p = 0.f;
    const float* crow = cache + s * DIM;
    for (int j = l; j < DIM; j += 64) p += crow[j] * wrow[768 + j];
    p = wave_red_sum(p);
    if (l == 0) brow[768 + s] = f2bf(p);
  }
  if (t < KP - 793) brow[793 + t] = 0;
  if (n < 32) {
    for (int d = t; d < DIM; d += 256)
      Cbf[n * DIM + d] = (n < MSLOT) ? f2bf(cache[n * DIM + d]) : (unsigned short)0;
  }
}

// ---------- convert f32 row -> bf16 row + 1/||row|| ----------
__global__ __launch_bounds__(256) void k_conv(const float* __restrict__ X,
                                              unsigned short* __restrict__ Xb, int ldb,
                                              float* __restrict__ rn, int pad) {
  int wglob = (blockIdx.x * 256 + threadIdx.x) >> 6;
  int l = threadIdx.x & 63;
  int nw = (gridDim.x * 256) >> 6;
  for (int row = wglob; row < C_TOK; row += nw) {
    const float4* src = (const float4*)(X + (size_t)row * DIM);
    unsigned short* dst = Xb + (size_t)row * ldb;
    float s = 0.f;
    float4 v[3];
    #pragma unroll
    for (int t = 0; t < 3; t++) {
      v[t] = src[l + 64 * t];
      s += v[t].x * v[t].x + v[t].y * v[t].y + v[t].z * v[t].z + v[t].w * v[t].w;
    }
    s = wave_red_sum(s);
    if (l == 0) rn[row] = 1.f / fmaxf(sqrtf(s), 1e-12f);
    #pragma unroll
    for (int t = 0; t < 3; t++) {
      ushort4 u;
      u.x = f2bf(v[t].x); u.y = f2bf(v[t].y); u.z = f2bf(v[t].z); u.w = f2bf(v[t].w);
      *(ushort4*)(dst + 4 * (l + 64 * t)) = u;
    }
    if (pad && l < (KP - 793)) dst[793 + l] = 0;
  }
}

// ---------- skinny score GEMM: raw[M][32] = Xb[M][lda(:768)] @ Cbf^T ----------
__global__ __launch_bounds__(256) void k_score(const unsigned short* __restrict__ Xb, int lda,
                                               const unsigned short* __restrict__ Cbf,
                                               float* __restrict__ raw) {
  __shared__ __align__(16) unsigned short As[128][64];
  __shared__ __align__(16) unsigned short Bs[32][64];
  int t = threadIdx.x, wv = t >> 6, l = t & 63;
  int m0 = blockIdx.x * 128;
  f32x4 acc[2][2] = {};
  for (int kk = 0; kk < DIM; kk += 64) {
    #pragma unroll
    for (int r = 0; r < 4; r++) {
      int i16 = r * 256 + t;
      int row = i16 >> 3, ce = (i16 & 7) * 8;
      gload_lds16(Xb + (size_t)(m0 + row) * lda + kk + ce, (char*)&As[0][0] + i16 * 16);
    }
    {
      int row = t >> 3, ce = (t & 7) * 8;
      gload_lds16(Cbf + row * DIM + kk + ce, (char*)&Bs[0][0] + t * 16);
    }
    __syncthreads();
    #pragma unroll
    for (int k2 = 0; k2 < 2; k2++) {
      int ko = k2 * 32 + (l >> 4) * 8;
      short8 a[2], b[2];
      #pragma unroll
      for (int mi = 0; mi < 2; mi++) a[mi] = *(const short8*)&As[wv * 32 + mi * 16 + (l & 15)][ko];
      #pragma unroll
      for (int ni = 0; ni < 2; ni++) b[ni] = *(const short8*)&Bs[ni * 16 + (l & 15)][ko];
      #pragma unroll
      for (int mi = 0; mi < 2; mi++)
        #pragma unroll
        for (int ni = 0; ni < 2; ni++)
          acc[mi][ni] = __builtin_amdgcn_mfma_f32_16x16x32_bf16(a[mi], b[ni], acc[mi][ni], 0, 0, 0);
    }
    __syncthreads();
  }
  #pragma unroll
  for (int mi = 0; mi < 2; mi++)
    #pragma unroll
    for (int ni = 0; ni < 2; ni++)
      #pragma unroll
      for (int r = 0; r < 4; r++) {
        int grow = m0 + wv * 32 + mi * 16 + (l >> 4) * 4 + r;
        int gcol = ni * 16 + (l & 15);
        raw[(size_t)grow * 32 + gcol] = acc[mi][ni][r];
      }
}

// ---------- text: softmax over 25 slots -> bf16 S into A[:,768:793] ----------
__global__ __launch_bounds__(256) void k_text_soft(const float* __restrict__ raw,
                                                   const float* __restrict__ rn,
                                                   unsigned short* __restrict__ A) {
  int i = blockIdx.x * 256 + threadIdx.x;
  float r = rn[i];
  const float* rw = raw + (size_t)i * 32;
  float sc[MSLOT];
  float mx = -1e30f;
  #pragma unroll
  for (int s = 0; s < MSLOT; s++) { sc[s] = rw[s] * r; mx = fmaxf(mx, sc[s]); }
  float sum = 0.f;
  #pragma unroll
  for (int s = 0; s < MSLOT; s++) { sc[s] = __expf(sc[s] - mx); sum += sc[s]; }
  float inv = 1.f / sum;
  unsigned short* dst = A + (size_t)i * KP + 768;
  #pragma unroll
  for (int s = 0; s < MSLOT; s++) dst[s] = f2bf(sc[s] * inv);
}

// ---------- image: per-row argmax (first max) + per-column max ----------
__global__ __launch_bounds__(256) void k_img_route(const float* __restrict__ raw,
                                                   const float* __restrict__ rn,
                                                   int* __restrict__ idx,
                                                   float* __restrict__ scval,
                                                   unsigned int* __restrict__ cmax) {
  __shared__ unsigned int lcm[MSLOT];
  int t = threadIdx.x;
  if (t < MSLOT) lcm[t] = 0u;
  __syncthreads();
  int i = blockIdx.x * 256 + t;
  float r = rn[i];
  const float* rw = raw + (size_t)i * 32;
  float best = -1e30f; int bi = 0;
  #pragma unroll
  for (int s = 0; s < MSLOT; s++) {
    float v = rw[s] * r;
    atomicMax(&lcm[s], enc_f(v));
    if (v > best) { best = v; bi = s; }
  }
  idx[i] = bi; scval[i] = best;
  __syncthreads();
  if (t < MSLOT) atomicMax(&cmax[t], lcm[t]);
}

// ---------- segment sum into per-block partials ----------
__global__ __launch_bounds__(512) void k_seg(const unsigned short* __restrict__ Ibf,
                                             const int* __restrict__ idx,
                                             const float* __restrict__ scval,
                                             const float* __restrict__ rn,
                                             const unsigned int* __restrict__ cmax,
                                             float* __restrict__ partial,
                                             int* __restrict__ counts_p) {
  __shared__ float seg[MSLOT][DIM];
  __shared__ int cnt[MSLOT];
  int t = threadIdx.x;
  for (int j = t; j < MSLOT * DIM; j += 512) ((float*)seg)[j] = 0.f;
  if (t < MSLOT) cnt[t] = 0;
  __syncthreads();
  int wv = t >> 6, l = t & 63;
  int base = blockIdx.x * 256;
  for (int i = 0; i < 32; i++) {
    int row = base + wv * 32 + i;
    int id = idx[row];
    float wq = __expf(scval[row] - dec_f(cmax[id]));
    float scale = wq * rn[row];
    const ushort4* src = (const ushort4*)(Ibf + (size_t)row * DIM);
    if (l == 0) atomicAdd(&cnt[id], 1);
    int rot = (l >> 3) & 3;
    #pragma unroll
    for (int tt = 0; tt < 3; tt++) {
      ushort4 u = src[l + 64 * tt];
      float vals[4] = { bf2f(u.x) * scale, bf2f(u.y) * scale,
                        bf2f(u.z) * scale, bf2f(u.w) * scale };
      int e0 = 4 * (l + 64 * tt);
      #pragma unroll
      for (int c = 0; c < 4; c++) {
        int cc = (c + rot) & 3;
        atomicAdd(&seg[id][e0 + cc], vals[cc]);
      }
    }
  }
  __syncthreads();
  float* pdst = partial + (size_t)blockIdx.x * (MSLOT * DIM);
  for (int j = t; j < MSLOT * DIM; j += 512) pdst[j] = ((const float*)seg)[j];
  if (t < MSLOT) counts_p[blockIdx.x * MSLOT + t] = cnt[t];
}

// ---------- cache update: reduce partials, momentum, renormalize ----------
__global__ __launch_bounds__(256) void k_upd(const float* __restrict__ partial,
                                             const int* __restrict__ counts_p,
                                             const float* __restrict__ cache,
                                             float* __restrict__ out_cache) {
  __shared__ float red[256];
  __shared__ int credi[256];
  int s = blockIdx.x, t = threadIdx.x;
  credi[t] = counts_p[t * MSLOT + s];
  __syncthreads();
  for (int o = 128; o > 0; o >>= 1) { if (t < o) credi[t] += credi[t + o]; __syncthreads(); }
  int cnt = credi[0];
  float upd[3]; float ss = 0.f;
  #pragma unroll
  for (int q = 0; q < 3; q++) {
    int d = t + q * 256;
    float sum = 0.f;
    for (int b = 0; b < NB_SEG; b++) sum += partial[(size_t)b * (MSLOT * DIM) + s * DIM + d];
    float cv = cache[s * DIM + d];
    float u = (cnt > 0) ? (MOMENTUM * cv + (1.f - MOMENTUM) * sum) : cv;
    upd[q] = u; ss += u * u;
  }
  red[t] = ss; __syncthreads();
  for (int o = 128; o > 0; o >>= 1) { if (t < o) red[t] += red[t + o]; __syncthreads(); }
  float inv = 1.f / fmaxf(sqrtf(red[0]), 1e-12f);
  #pragma unroll
  for (int q = 0; q < 3; q++) out_cache[s * DIM + t + q * 256] = upd[q] * inv;
}

// ---------- main GEMM: out = ALPHA*(A[65536][832] @ Bt^T) + T(bf16) ----------
__global__ __launch_bounds__(256) void k_gemm(const unsigned short* __restrict__ A,
                                              const unsigned short* __restrict__ Bt,
                                              float* __restrict__ out) {
  __shared__ __align__(16) unsigned short As[128][64];
  __shared__ __align__(16) unsigned short Bs[128][64];
  int t = threadIdx.x, wv = t >> 6, l = t & 63;
  int wr = wv >> 1, wc = wv & 1;
  int m0 = blockIdx.y * 128, n0 = blockIdx.x * 128;
  f32x4 acc[4][4] = {};
  for (int kk = 0; kk < KP; kk += 64) {
    #pragma unroll
    for (int r = 0; r < 4; r++) {
      int i16 = r * 256 + t;
      int row = i16 >> 3, ce = (i16 & 7) * 8;
      gload_lds16(A + (size_t)(m0 + row) * KP + kk + ce, (char*)&As[0][0] + i16 * 16);
    }
    #pragma unroll
    for (int r = 0; r < 4; r++) {
      int i16 = r * 256 + t;
      int row = i16 >> 3, ce = (i16 & 7) * 8;
      gload_lds16(Bt + (size_t)(n0 + row) * KP + kk + ce, (char*)&Bs[0][0] + i16 * 16);
    }
    __syncthreads();
    #pragma unroll
    for (int k2 = 0; k2 < 2; k2++) {
      int ko = k2 * 32 + (l >> 4) * 8;
      short8 a[4], b[4];
      #pragma unroll
      for (int mi = 0; mi < 4; mi++) a[mi] = *(const short8*)&As[wr * 64 + mi * 16 + (l & 15)][ko];
      #pragma unroll
      for (int ni = 0; ni < 4; ni++) b[ni] = *(const short8*)&Bs[wc * 64 + ni * 16 + (l & 15)][ko];
      #pragma unroll
      for (int mi = 0; mi < 4; mi++)
        #pragma unroll
        for (int ni = 0; ni < 4; ni++)
          acc[mi][ni] = __builtin_amdgcn_mfma_f32_16x16x32_bf16(a[mi], b[ni], acc[mi][ni], 0, 0, 0);
    }
    __syncthreads();
  }
  #pragma unroll
  for (int mi = 0; mi < 4; mi++) {
    #pragma unroll
    for (int ni = 0; ni < 4; ni++) {
      int gcol = n0 + wc * 64 + ni * 16 + (l & 15);
      #pragma unroll
      for (int r = 0; r < 4; r++) {
        int grow = m0 + wr * 64 + mi * 16 + (l >> 4) * 4 + r;
        float tv = bf2f(A[(size_t)grow * KP + gcol]);
        out[(size_t)grow * DIM + gcol] = ALPHA * acc[mi][ni][r] + tv;
      }
    }
  }
}

// ---------- loss: mean |normalize(tff) - T| ----------
__global__ __launch_bounds__(256) void k_loss(const float* __restrict__ outv,
                                              const unsigned short* __restrict__ A,
                                              float* __restrict__ lacc) {
  __shared__ float bacc[4];
  int t = threadIdx.x, wv = t >> 6, l = t & 63;
  int wglob = (blockIdx.x * 256 + t) >> 6;
  int nw = (gridDim.x * 256) >> 6;
  float local = 0.f;
  for (int row = wglob; row < C_TOK; row += nw) {
    const float4* src = (const float4*)(outv + (size_t)row * DIM);
    float4 v[3]; float s = 0.f;
    #pragma unroll
    for (int tt = 0; tt < 3; tt++) {
      v[tt] = src[l + 64 * tt];
      s += v[tt].x * v[tt].x + v[tt].y * v[tt].y + v[tt].z * v[tt].z + v[tt].w * v[tt].w;
    }
    s = wave_red_sum(s);
    float inv = 1.f / fmaxf(sqrtf(s), 1e-12f);
    const ushort4* tsrc = (const ushort4*)(A + (size_t)row * KP);
    float d = 0.f;
    #pragma unroll
    for (int tt = 0; tt < 3; tt++) {
      ushort4 u = tsrc[l + 64 * tt];
      d += fabsf(v[tt].x * inv - bf2f(u.x)) + fabsf(v[tt].y * inv - bf2f(u.y))
         + fabsf(v[tt].z * inv - bf2f(u.z)) + fabsf(v[tt].w * inv - bf2f(u.w));
    }
    local += d;
  }
  local = wave_red_sum(local);
  if (l == 0) bacc[wv] = local;
  __syncthreads();
  if (t == 0) atomicAdd(lacc, bacc[0] + bacc[1] + bacc[2] + bacc[3]);
}

__global__ void k_final(const float* __restrict__ lacc, float* __restrict__ out_loss) {
  *out_loss = *lacc / (float)((size_t)C_TOK * DIM);
}

extern "C" void kernel_launch(void* const* d_in, const int* in_sizes, int n_in,
                              void* d_out, int out_size, void* d_ws, size_t ws_size,
                              hipStream_t stream) {
  if (ws_size < WS_NEED) return;
  const float* text  = (const float*)d_in[0];
  const float* image = (const float*)d_in[1];
  const float* w     = (const float*)d_in[2];
  const float* cache = (const float*)d_in[3];
  float* out = (float*)d_out;

  char* ws = (char*)d_ws;
  unsigned short* Bt  = (unsigned short*)(ws + OFF_BT);
  unsigned short* Cbf = (unsigned short*)(ws + OFF_CBF);
  unsigned int* cmax  = (unsigned int*)(ws + OFF_CMAX);
  float* lacc         = (float*)(ws + OFF_LACC);
  char* big = ws + OFF_BIG;
  // image phase
  unsigned short* Ibf = (unsigned short*)(big + BO_IBF);
  float* rawI = (float*)(big + BO_RAWI);
  float* part = (float*)(big + BO_PART);
  int*   idxp = (int*)(big + BO_IDX);
  float* scv  = (float*)(big + BO_SCV);
  float* rnI  = (float*)(big + BO_RNI);
  int*   cntp = (int*)(big + BO_CNTP);
  // text phase (reuses big region after image phase completes)
  unsigned short* A = (unsigned short*)(big + BO_A);
  float* rawT = (float*)(big + BO_RAWT);
  float* rnT  = (float*)(big + BO_RNT);

  hipMemsetAsync(cmax, 0, 128, stream);
  hipMemsetAsync(lacc, 0, 128, stream);

  k_build_b<<<768, 256, 0, stream>>>(w, cache, Bt, Cbf);

  // ---- image / write path ----
  k_conv<<<2048, 256, 0, stream>>>(image, Ibf, DIM, rnI, 0);
  k_score<<<512, 256, 0, stream>>>(Ibf, DIM, Cbf, rawI);
  k_img_route<<<256, 256, 0, stream>>>(rawI, rnI, idxp, scv, cmax);
  k_seg<<<NB_SEG, 512, 0, stream>>>(Ibf, idxp, scv, rnI, cmax, part, cntp);
  k_upd<<<MSLOT, 256, 0, stream>>>(part, cntp, cache, out + (size_t)C_TOK * DIM + 1);

  // ---- text / read path ----
  k_conv<<<2048, 256, 0, stream>>>(text, A, KP, rnT, 1);
  k_score<<<512, 256, 0, stream>>>(A, KP, Cbf, rawT);
  k_text_soft<<<256, 256, 0, stream>>>(rawT, rnT, A);
  k_gemm<<<dim3(6, 512), 256, 0, stream>>>(A, Bt, out);
  k_loss<<<2048, 256, 0, stream>>>(out, A, lacc);
  k_final<<<1, 1, 0, stream>>>(lacc, out + (size_t)C_TOK * DIM);
}